// Round 14
// baseline (160.554 us; speedup 1.0000x reference)
//
#include <hip/hip_runtime.h>
#include <hip/hip_bf16.h>

#define EMB 768
#define HD 1024
#define D3 128
#define CTXN 512
#define BB 8
#define SS 64

typedef __hip_bfloat16 bf16;
typedef __attribute__((ext_vector_type(8))) short short8v;
typedef __attribute__((ext_vector_type(4))) float f32x4;

__device__ __forceinline__ float fast_tanh(float x) {
  float e = __expf(2.f * x);
  return 1.f - 2.f * __builtin_amdgcn_rcpf(e + 1.f);
}

struct GDesc {
  const void* A;                 // row-major [M][K], fp32 or bf16
  const bf16* BT;                // transposed B: [N][K] bf16
  const int* arowmap;            // optional A row gather
  const float* addrow_f;         // added to row M-1 only
  const float* bias_f;           // added to all rows
  float* Cf;                     // fp32 out
  bf16* Cb;                      // bf16 out
  bf16* CbT;                     // bf16 transposed out [N][ldct]
  float* brow_f;                 // fp32 copy of row M-1
  int M, N, K, lda, ldbt, ldct, af32, mtiles, blk0, nblks;
};
struct GBatch {
  GDesc d[10]; int nd;
  // katt-mode blocks appended after katt0 (katt0 = big sentinel if none)
  int katt0, katt_toff;
  const float* qF; const float* qH; const float* ctxp; const float* V;
  float* out;
};

__device__ void katt_tile(const GBatch& bat, int i, char* SM) {
  auto lq = (float(*)[128])SM;            // 16 KB
  auto lc = (float(*)[132])(SM + 16384);  // 16.9 KB
  float* lv = (float*)(SM + 33792);       // 512 B
  int tid = threadIdx.x;
  int b = i >> 4, ct = i & 15, tt = bat.katt_toff;
  int t0 = tt * 32, c0 = ct * 32;
  for (int k = tid; k < 32 * 128; k += 256) {
    int r = k >> 7, d = k & 127;
    int t = t0 + r;
    lq[r][d] = bat.qF[((long)t * 8 + b) * 128 + d] +
               bat.qH[(((long)(t & 7)) * 64 + (t >> 3) * 8 + b) * 128 + d];
    lc[r][d] = bat.ctxp[((long)b * CTXN + c0 + r) * D3 + d];
  }
  if (tid < 128) lv[tid] = bat.V[tid];
  __syncthreads();
  int cl = tid & 31, tg = tid >> 5;
  float r4[4] = {0.f, 0.f, 0.f, 0.f};
  for (int d4 = 0; d4 < 32; ++d4) {
    float4 cv = *reinterpret_cast<const float4*>(&lc[cl][d4 * 4]);
    float4 vv = *reinterpret_cast<const float4*>(&lv[d4 * 4]);
#pragma unroll
    for (int u = 0; u < 4; ++u) {
      int t = tg + u * 8;
      float4 qv = *reinterpret_cast<const float4*>(&lq[t][d4 * 4]);
      r4[u] = fmaf(vv.x, fast_tanh(qv.x + cv.x), r4[u]);
      r4[u] = fmaf(vv.y, fast_tanh(qv.y + cv.y), r4[u]);
      r4[u] = fmaf(vv.z, fast_tanh(qv.z + cv.z), r4[u]);
      r4[u] = fmaf(vv.w, fast_tanh(qv.w + cv.w), r4[u]);
    }
  }
#pragma unroll
  for (int u = 0; u < 4; ++u) {
    int t = tg + u * 8;
    bat.out[((long)b * SS + (t0 + t)) * CTXN + c0 + cl] = r4[u];
  }
  if (i == 0 && tt == 0) {
    for (int k = tid; k < SS * BB; k += 256)
      bat.out[(long)BB * SS * CTXN + k] = 0.f;
  }
}

// gemmz: 32x64 tile, BK=128, 4 waves, XOR-swizzled dbuf LDS (r6-proven body),
// with appended katt-mode blocks.
__global__ __launch_bounds__(256) void gemmz(GBatch bat) {
  __shared__ __align__(16) char SM[49152];  // As 16KB | Bs 32KB (katt overlays)
  int bx = blockIdx.x;
  if (bx >= bat.katt0) {
    katt_tile(bat, bx - bat.katt0, SM);
    return;
  }
  auto As = (bf16(*)[32][128])SM;
  auto Bs = (bf16(*)[64][128])(SM + 16384);

  GDesc d = bat.d[0];
  for (int i = 1; i < bat.nd; ++i)
    if (bx >= bat.d[i].blk0) d = bat.d[i];
  int local = bx - d.blk0;
  int mt = local % d.mtiles, nt = local / d.mtiles;
  int bm0 = mt * 32, bn0 = nt * 64;

  int tid = threadIdx.x, lane = tid & 63, wid = tid >> 6;
  int l16 = lane & 15, g = lane >> 4;
  int wm = (wid & 1) * 16, wn = (wid >> 1) * 32;
  int arow = tid >> 3, aseg = tid & 7;
  int brow = tid >> 2, bseg = tid & 3;
  f32x4 acc[2] = {};

  int agr = bm0 + arow;
  int asrc = (agr < d.M) ? (d.arowmap ? d.arowmap[agr] : agr) : -1;
  const float* Af = (const float*)d.A;
  const bf16* Ab = (const bf16*)d.A;

  float fa[16];
  short8v ba0 = {}, ba1 = {}, bb0 = {}, bb1 = {}, bb2 = {}, bb3 = {};
  int nk = d.K >> 7;

  auto LD = [&](int k0) {
    if (d.af32) {
      if (asrc >= 0) {
        const float* s = Af + (long)asrc * d.lda + k0 + aseg * 16;
#pragma unroll
        for (int j = 0; j < 16; ++j) fa[j] = s[j];
      } else {
#pragma unroll
        for (int j = 0; j < 16; ++j) fa[j] = 0.f;
      }
    } else {
      if (asrc >= 0) {
        const bf16* s = Ab + (long)asrc * d.lda + k0 + aseg * 16;
        ba0 = *(const short8v*)s;
        ba1 = *(const short8v*)(s + 8);
      } else {
        short8v z = {};
        ba0 = z; ba1 = z;
      }
    }
    const bf16* bsrc = d.BT + (long)(bn0 + brow) * d.ldbt + k0 + bseg * 32;
    bb0 = *(const short8v*)bsrc;
    bb1 = *(const short8v*)(bsrc + 8);
    bb2 = *(const short8v*)(bsrc + 16);
    bb3 = *(const short8v*)(bsrc + 24);
  };
  auto ST = [&](int buf) {
    int rs = arow & 7;
    if (d.af32) {
      bf16 t8[16];
#pragma unroll
      for (int j = 0; j < 16; ++j) t8[j] = __float2bfloat16(fa[j]);
      *(short8v*)&As[buf][arow][((2 * aseg) ^ rs) * 8] = *(short8v*)t8;
      *(short8v*)&As[buf][arow][((2 * aseg + 1) ^ rs) * 8] = *(short8v*)(t8 + 8);
    } else {
      *(short8v*)&As[buf][arow][((2 * aseg) ^ rs) * 8] = ba0;
      *(short8v*)&As[buf][arow][((2 * aseg + 1) ^ rs) * 8] = ba1;
    }
    int rb = brow & 7;
    *(short8v*)&Bs[buf][brow][((4 * bseg) ^ rb) * 8] = bb0;
    *(short8v*)&Bs[buf][brow][((4 * bseg + 1) ^ rb) * 8] = bb1;
    *(short8v*)&Bs[buf][brow][((4 * bseg + 2) ^ rb) * 8] = bb2;
    *(short8v*)&Bs[buf][brow][((4 * bseg + 3) ^ rb) * 8] = bb3;
  };

  LD(0);
  ST(0);
  __syncthreads();
  for (int it = 0; it < nk; ++it) {
    int cur = it & 1;
    if (it + 1 < nk) LD((it + 1) << 7);
    int ar = wm + l16;
    int ars = ar & 7;
#pragma unroll
    for (int kf = 0; kf < 4; ++kf) {
      short8v a = *(const short8v*)&As[cur][ar][((kf * 4 + g) ^ ars) * 8];
#pragma unroll
      for (int j = 0; j < 2; ++j) {
        int br = wn + j * 16 + l16;
        short8v b = *(const short8v*)&Bs[cur][br][((kf * 4 + g) ^ (br & 7)) * 8];
        acc[j] = __builtin_amdgcn_mfma_f32_16x16x32_bf16(a, b, acc[j], 0, 0, 0);
      }
    }
    if (it + 1 < nk) ST(cur ^ 1);
    __syncthreads();
  }

  float* Cs = (float*)(SM + 16384);  // overlay Bs: [64][33] floats
  bool doT = (d.CbT != nullptr);
#pragma unroll
  for (int j = 0; j < 2; ++j)
#pragma unroll
    for (int r = 0; r < 4; ++r) {
      int gl = wm + g * 4 + r, cl = wn + j * 16 + l16;
      int grow = bm0 + gl, gcol = bn0 + cl;
      float v = acc[j][r];
      if (d.bias_f) v += d.bias_f[gcol];
      if (d.addrow_f && grow == d.M - 1) v += d.addrow_f[gcol];
      if (grow < d.M) {
        if (d.Cf) d.Cf[(long)grow * d.N + gcol] = v;
        if (d.Cb) d.Cb[(long)grow * d.N + gcol] = __float2bfloat16(v);
        if (d.brow_f && grow == d.M - 1) d.brow_f[gcol] = v;
      }
      if (doT) Cs[cl * 33 + gl] = v;
    }
  if (doT) {
    __syncthreads();
    int ctrows = d.M < 1024 ? d.M : 1024;
    int n = tid >> 2, ms = (tid & 3) * 8;
    int gm0 = bm0 + ms;
    bf16 t8[8];
#pragma unroll
    for (int jj = 0; jj < 8; ++jj) t8[jj] = __float2bfloat16(Cs[n * 33 + ms + jj]);
    if (gm0 + 7 < ctrows) {
      *(short8v*)&d.CbT[(long)(bn0 + n) * d.ldct + gm0] = *(short8v*)t8;
    } else {
#pragma unroll
      for (int jj = 0; jj < 8; ++jj)
        if (gm0 + jj < ctrows) d.CbT[(long)(bn0 + n) * d.ldct + gm0 + jj] = t8[jj];
    }
  }
}

// kcast: Maug1 bf16, transposes, g0, qb, rowmap (r6 verbatim)
__global__ __launch_bounds__(256) void kcast(const float* __restrict__ W_s,
                                             const float* __restrict__ b_s,
                                             const float* __restrict__ context,
                                             const float* __restrict__ b_in,
                                             const float* __restrict__ W_att_in,
                                             const float* __restrict__ b_att_in,
                                             const float* __restrict__ W_att_h,
                                             const int* __restrict__ ids,
                                             bf16* __restrict__ Mb0,
                                             bf16* __restrict__ Mb0T,
                                             bf16* __restrict__ Y0T,
                                             bf16* __restrict__ WahT,
                                             bf16* __restrict__ WaiT,
                                             bf16* __restrict__ Gb,
                                             float* __restrict__ qb,
                                             int* __restrict__ rowmap) {
  int blk = blockIdx.x, tid = threadIdx.x;
  __shared__ bf16 tl[64][65];
  __shared__ float red[2][128];

  auto TP = [&](const float* src, int R, int C, bf16* dst, int tr, int tc) {
    int r0 = tr * 64, c0 = tc * 64;
    {
      int r = tid >> 2, cs = (tid & 3) * 16;
      const float* s = src + (long)(r0 + r) * C + c0 + cs;
#pragma unroll
      for (int j = 0; j < 16; ++j) tl[cs + j][r] = __float2bfloat16(s[j]);
    }
    __syncthreads();
    {
      int c = tid >> 2, rs = (tid & 3) * 16;
      bf16 o[16];
#pragma unroll
      for (int j = 0; j < 16; ++j) o[j] = tl[c][rs + j];
      *(short8v*)&dst[(long)(c0 + c) * R + r0 + rs] = *(short8v*)&o[0];
      *(short8v*)&dst[(long)(c0 + c) * R + r0 + rs + 8] = *(short8v*)&o[8];
    }
  };

  if (blk < 256) {
    long base = (long)blk * 4096;
    for (int i = tid; i < 4096; i += 256)
      Mb0[base + i] = __float2bfloat16(W_s[base + i]);
  } else if (blk == 256) {
    for (int i = tid; i < HD; i += 256)
      Mb0[(long)HD * HD + i] = __float2bfloat16(b_s[i]);
  } else if (blk < 513) {
    int t = blk - 257;
    TP(W_s, 1024, 1024, Mb0T, t >> 4, t & 15);
  } else if (blk < 545) {
    int t = blk - 513;
    TP(W_att_in + (long)1024 * D3, 1024, 128, Y0T, t >> 1, t & 1);
  } else if (blk < 577) {
    int t = blk - 545;
    TP(W_att_h, 1024, 128, WahT, t >> 1, t & 1);
  } else if (blk < 609) {
    int t = blk - 577;
    TP(W_att_in, 1024, 128, WaiT, t >> 1, t & 1);
  } else if (blk == 609) {
    for (int i = tid; i < BB * HD; i += 256) {
      int b = i >> 10, k = i & 1023;
      Gb[i] = __float2bfloat16(context[((long)b * CTXN + CTXN - 1) * HD + k]);
    }
  } else if (blk == 610) {
    int dd = tid & 127, h = tid >> 7;
    float acc = 0.f;
    for (int k = h * 512; k < h * 512 + 512; ++k)
      acc += b_in[k] * W_att_in[k * D3 + dd];
    red[h][dd] = acc;
    __syncthreads();
    if (h == 0) qb[dd] = red[0][dd] + red[1][dd] + b_att_in[dd];
  } else {
    for (int i = tid; i < 512; i += 256) {
      int t = i >> 3, b = i & 7;
      rowmap[i] = ids[b * SS + t];
    }
  }
}

static inline GDesc mk(const void* A, int af32, int lda, const int* arowmap,
                       const bf16* BT, int ldbt, int M, int N, int K,
                       const float* addrow_f, const float* bias_f, float* Cf,
                       bf16* Cb, bf16* CbT, int ldct, float* brow_f, int blk0) {
  GDesc d;
  d.A = A; d.BT = BT; d.arowmap = arowmap;
  d.addrow_f = addrow_f; d.bias_f = bias_f;
  d.Cf = Cf; d.Cb = Cb; d.CbT = CbT; d.brow_f = brow_f;
  d.M = M; d.N = N; d.K = K; d.lda = lda; d.ldbt = ldbt; d.ldct = ldct;
  d.af32 = af32;
  d.mtiles = (M + 31) >> 5;
  d.blk0 = blk0;
  d.nblks = d.mtiles * (N >> 6);
  return d;
}

extern "C" void kernel_launch(void* const* d_in, const int* in_sizes, int n_in,
                              void* d_out, int out_size, void* d_ws, size_t ws_size,
                              hipStream_t stream) {
  const int* ids = (const int*)d_in[0];
  const float* context = (const float*)d_in[4];
  const float* emb = (const float*)d_in[5];
  const float* W_in = (const float*)d_in[6];
  const float* b_in = (const float*)d_in[7];
  const float* W_s = (const float*)d_in[8];
  const float* b_s = (const float*)d_in[9];
  const float* W_att_in = (const float*)d_in[10];
  const float* b_att_in = (const float*)d_in[11];
  const float* W_att_h = (const float*)d_in[12];
  const float* b_att_h = (const float*)d_in[13];
  const float* V = (const float*)d_in[14];

  float* ws = (float*)d_ws;
  float* ctxp = ws;                     // 524288
  float* Yf = ctxp + 524288;            // 9*131200
  float* qF = Yf + 1180800;             // 65536
  float* qH = qF + 65536;               // 65536
  float* qb = qH + 65536;               // 128
  float* brow2 = qb + 128;
  float* brow4 = brow2 + 1024;
  float* brow8 = brow4 + 1024;
  float* brow16 = brow8 + 1024;
  float* brow32 = brow16 + 1024;
  int* rowmap = (int*)(brow32 + 1024);
  bf16* bfp = (bf16*)(rowmap + 512);
  bf16* Mb0 = bfp;                      // 1025*1024
  bf16* Mb0T = Mb0 + 1049600;
  bf16* Mb1 = Mb0T + 1048576;
  bf16* Mb1T = Mb1 + 1049600;
  bf16* Mb2 = Mb1T + 1048576;
  bf16* Mb2T = Mb2 + 1049600;
  bf16* Mb3 = Mb2T + 1048576;
  bf16* Mb3T = Mb3 + 1049600;
  bf16* YT = Mb3T + 1048576;            // 9 slots * 131072
  bf16* WahT = YT + 9 * 131072;
  bf16* WaiT = WahT + 131072;
  bf16* WcT = WaiT + 131072;
  bf16* Gb = WcT + 131072;              // 64*1024
  float* out = (float*)d_out;

  auto Yfr = [&](int r) { return Yf + (long)r * 131200; };
  auto YTs = [&](int r) { return YT + (long)r * 131072; };
  const int NOKATT = 1 << 30;

  auto setk = [&](GBatch& bt, int katt0, int toff) {
    bt.katt0 = katt0; bt.katt_toff = toff;
    bt.qF = qF; bt.qH = qH; bt.ctxp = ctxp; bt.V = V; bt.out = out;
  };

  kcast<<<dim3(612), dim3(256), 0, stream>>>(W_s, b_s, context, b_in, W_att_in,
                                             b_att_in, W_att_h, ids, Mb0, Mb0T,
                                             YTs(0), WahT, WaiT, Gb, qb, rowmap);
  // L1: M2 ; Z1 ; ctx_proj ; WcT
  {
    GBatch bt{}; int c = 0;
    bt.d[0] = mk(Mb0, 0, 1024, nullptr, Mb0T, 1024, 1025, 1024, 1024, b_s, nullptr, nullptr, Mb1, Mb1T, 1024, brow2, c); c += bt.d[0].nblks;
    bt.d[1] = mk(Mb0, 0, 1024, nullptr, YTs(0), 1024, 1025, 128, 1024, nullptr, nullptr, Yfr(1), nullptr, YTs(1), 1024, nullptr, c); c += bt.d[1].nblks;
    bt.d[2] = mk(context, 1, 1024, nullptr, WahT, 1024, 4096, 128, 1024, nullptr, b_att_h, ctxp, nullptr, nullptr, 0, nullptr, c); c += bt.d[2].nblks;
    bt.d[3] = mk(W_in, 1, 1024, nullptr, WaiT, 1024, 768, 128, 1024, nullptr, nullptr, nullptr, nullptr, WcT, 768, nullptr, c); c += bt.d[3].nblks;
    bt.nd = 4; setk(bt, NOKATT, 0);
    gemmz<<<dim3(c), dim3(256), 0, stream>>>(bt);
  }
  // L2: M4 ; Z2 ; Z3 ; qF
  {
    GBatch bt{}; int c = 0;
    bt.d[0] = mk(Mb1, 0, 1024, nullptr, Mb1T, 1024, 1025, 1024, 1024, brow2, nullptr, nullptr, Mb2, Mb2T, 1024, brow4, c); c += bt.d[0].nblks;
    bt.d[1] = mk(Mb1, 0, 1024, nullptr, YTs(0), 1024, 1025, 128, 1024, nullptr, nullptr, Yfr(2), nullptr, YTs(2), 1024, nullptr, c); c += bt.d[1].nblks;
    bt.d[2] = mk(Mb1, 0, 1024, nullptr, YTs(1), 1024, 1025, 128, 1024, Yfr(1) + 131072, nullptr, Yfr(3), nullptr, YTs(3), 1024, nullptr, c); c += bt.d[2].nblks;
    bt.d[3] = mk(emb, 1, 768, rowmap, WcT, 768, 512, 128, 768, nullptr, qb, qF, nullptr, nullptr, 0, nullptr, c); c += bt.d[3].nblks;
    bt.nd = 4; setk(bt, NOKATT, 0);
    gemmz<<<dim3(c), dim3(256), 0, stream>>>(bt);
  }
  // L3: M8 ; Z4..Z7
  {
    GBatch bt{}; int c = 0;
    bt.d[0] = mk(Mb2, 0, 1024, nullptr, Mb2T, 1024, 1025, 1024, 1024, brow4, nullptr, nullptr, Mb3, Mb3T, 1024, brow8, c); c += bt.d[0].nblks;
    for (int s = 0; s < 4; ++s) {
      bt.d[1 + s] = mk(Mb2, 0, 1024, nullptr, YTs(s), 1024, 1025, 128, 1024,
                       (s == 0) ? nullptr : (Yfr(s) + 131072), nullptr,
                       Yfr(4 + s), nullptr, YTs(4 + s), 1024, nullptr, c);
      c += bt.d[1 + s].nblks;
    }
    bt.nd = 5; setk(bt, NOKATT, 0);
    gemmz<<<dim3(c), dim3(256), 0, stream>>>(bt);
  }
  // L4: M16 ; Z8 ; g1
  {
    GBatch bt{}; int c = 0;
    bt.d[0] = mk(Mb3, 0, 1024, nullptr, Mb3T, 1024, 1025, 1024, 1024, brow8, nullptr, nullptr, Mb1, Mb1T, 1024, brow16, c); c += bt.d[0].nblks;
    bt.d[1] = mk(Mb3, 0, 1024, nullptr, YTs(0), 1024, 1025, 128, 1024, nullptr, nullptr, Yfr(8), nullptr, YTs(8), 1024, nullptr, c); c += bt.d[1].nblks;
    bt.d[2] = mk(Gb, 0, 1024, nullptr, Mb3T, 1024, 8, 1024, 1024, nullptr, brow8, nullptr, Gb + 8192, nullptr, 0, nullptr, c); c += bt.d[2].nblks;
    bt.nd = 3; setk(bt, NOKATT, 0);
    gemmz<<<dim3(c), dim3(256), 0, stream>>>(bt);
  }
  // L5: M32 ; [g2,g3] ; qH(k=0, r=1..8)  (g0 + Z1..8 ready)
  {
    GBatch bt{}; int c = 0;
    bt.d[0] = mk(Mb1, 0, 1024, nullptr, Mb1T, 1024, 1025, 1024, 1024, brow16, nullptr, nullptr, Mb2, Mb2T, 1024, brow32, c); c += bt.d[0].nblks;
    bt.d[1] = mk(Gb, 0, 1024, nullptr, Mb1T, 1024, 16, 1024, 1024, nullptr, brow16, nullptr, Gb + 16384, nullptr, 0, nullptr, c); c += bt.d[1].nblks;
    for (int r = 1; r <= 8; ++r) {
      bt.d[1 + r] = mk(Gb, 0, 1024, nullptr, YTs(r), 1024, 8, 128, 1024, nullptr,
                       Yfr(r) + 131072, qH + (long)(r - 1) * 8192, nullptr, nullptr,
                       0, nullptr, c);
      c += bt.d[1 + r].nblks;
    }
    bt.nd = 10; setk(bt, NOKATT, 0);
    gemmz<<<dim3(c), dim3(256), 0, stream>>>(bt);
  }
  // L6: [g4..g7] ; qH(k=1..3, r=1..8)
  {
    GBatch bt{}; int c = 0;
    bt.d[0] = mk(Gb, 0, 1024, nullptr, Mb2T, 1024, 32, 1024, 1024, nullptr, brow32, nullptr, Gb + 32768, nullptr, 0, nullptr, c); c += bt.d[0].nblks;
    for (int r = 1; r <= 8; ++r) {
      bt.d[r] = mk(Gb + 8192, 0, 1024, nullptr, YTs(r), 1024, 24, 128, 1024, nullptr,
                   Yfr(r) + 131072, qH + (long)(r - 1) * 8192 + 1024, nullptr,
                   nullptr, 0, nullptr, c);
      c += bt.d[r].nblks;
    }
    bt.nd = 9; setk(bt, NOKATT, 0);
    gemmz<<<dim3(c), dim3(256), 0, stream>>>(bt);
  }
  // L7: qH(k=4..7, r=1..8) ∥ katt(t=0..31)
  {
    GBatch bt{}; int c = 0;
    for (int r = 1; r <= 8; ++r) {
      bt.d[r - 1] = mk(Gb + 32768, 0, 1024, nullptr, YTs(r), 1024, 32, 128, 1024,
                       nullptr, Yfr(r) + 131072,
                       qH + (long)(r - 1) * 8192 + 4096, nullptr, nullptr, 0,
                       nullptr, c);
      c += bt.d[r - 1].nblks;
    }
    bt.nd = 8; setk(bt, c, 0);
    gemmz<<<dim3(c + 128), dim3(256), 0, stream>>>(bt);
  }
  // L8: katt(t=32..63)
  {
    GBatch bt{};
    bt.nd = 0; setk(bt, 0, 1);
    gemmz<<<dim3(128), dim3(256), 0, stream>>>(bt);
  }
}